// Round 13
// baseline (41.283 us; speedup 1.0000x reference)
//
#include <hip/hip_runtime.h>

#define NOUT 83
#define NHEART 27
#define NLUNG 28

typedef float v4f __attribute__((ext_vector_type(4)));

// forced 16B non-temporal global load (nt: bypass L1 allocation — R12's
// proven win; volatile asm: compiler cannot split/shrink the pipeline)
#define GLOADNT(dst, ptr, offs) \
    asm volatile("global_load_dwordx4 %0, %1, off offset:" offs " nt" \
                 : "=v"(dst) : "v"(ptr))

#define WAITV(lit) \
    asm volatile("s_waitcnt vmcnt(" lit ")" ::: "memory"); \
    __builtin_amdgcn_sched_barrier(0)

// Block: 576 threads = 9 waves, owns 4 volumes; thread = one (v,q) quad
// position (tid = v*144+q), reads its 15 slices at stride 2304 B through
// an 8-deep rolling asm pipeline into ONE float4 accumulator.
// VGPR budget ~50 (t[8]=32 + acc + ptr) -> <=64 -> 8 waves/SIMD tier:
// 3 blocks/CU resident = 27 waves/CU (vs 16 for the sequential-scan
// variants whose acc[9] forced the 128-VGPR tier).
// FC: 36 groups x 16 lanes; group g -> rows o = g+36k (k<3) x 4 vols.
__global__ __launch_bounds__(576, 8) void bodyavg_stride8(
    const v4f* __restrict__ x4,      // [B*2160] quads
    const float* __restrict__ dzh,   // [27,16]
    const float* __restrict__ dzl,   // [28,16]
    const v4f* __restrict__ fcw4,    // [83,144] quads
    const float* __restrict__ fcb,   // [83]
    float* __restrict__ out,         // [B,83]
    int B)
{
    __shared__ float attn_lds[NOUT * 17];
    __shared__ v4f   xms[576];           // per-volume slice-SUM, tid-linear

    const int tid = threadIdx.x;
    const int blk = blockIdx.x;
    const int b0  = blk * 4;

    const int v = tid / 144;      // volume slot 0..3
    const int q = tid - v * 144;  // quad position 0..143
    const int b = b0 + v;

    // ---- Phase 1: 15 strided loads, 8-deep rolling pipeline, acc = 1 ----
    v4f acc = {0.f, 0.f, 0.f, 0.f};
    if (b < B) {
        const v4f* P = x4 + (size_t)b * 2160 + q;
        v4f t[8];
        // preload s = 0..7 (offset pairs 0 / 2304 B, advance 288 quads)
        GLOADNT(t[0], P, "0"); GLOADNT(t[1], P, "2304"); P += 288;
        GLOADNT(t[2], P, "0"); GLOADNT(t[3], P, "2304"); P += 288;
        GLOADNT(t[4], P, "0"); GLOADNT(t[5], P, "2304"); P += 288;
        GLOADNT(t[6], P, "0"); GLOADNT(t[7], P, "2304"); P += 288;
        // consume s=0..6, reissue s=8..14 (always 8 outstanding)
        #pragma unroll
        for (int u = 0; u < 7; ++u) {
            WAITV("7");
            acc += t[u];
            GLOADNT(t[u], P, "0");
            P += 144;
        }
        // drain: outstanding oldest-first = t[7](s7), t[0](s8)..t[6](s14)
        WAITV("7"); acc += t[7];
        WAITV("6"); acc += t[0];
        WAITV("5"); acc += t[1];
        WAITV("4"); acc += t[2];
        WAITV("3"); acc += t[3];
        WAITV("2"); acc += t[4];
        WAITV("1"); acc += t[5];
        WAITV("0"); acc += t[6];
    }
    xms[tid] = acc;               // raw sum; 1/15 folded into attn

    // ---- Phase 0: channel softmax (1/15 folded in), off critical path ----
    if (tid < NOUT) {
        const int o = tid;
        const float* row = (o < NHEART) ? (dzh + o * 16)
                                        : (dzl + ((o - NHEART) % NLUNG) * 16);
        float vals[16];
        #pragma unroll
        for (int c = 0; c < 16; ++c) vals[c] = row[c];
        float m = vals[0];
        #pragma unroll
        for (int c = 1; c < 16; ++c) m = fmaxf(m, vals[c]);
        float s = 0.f;
        #pragma unroll
        for (int c = 0; c < 16; ++c) { vals[c] = expf(vals[c] - m); s += vals[c]; }
        const float inv = (1.0f / s) * (1.0f / 15.0f);
        #pragma unroll
        for (int c = 0; c < 16; ++c) attn_lds[o * 17 + c] = vals[c] * inv;
    }

    __syncthreads();

    // ---- Phase 2: FC. 36 groups of 16 lanes; rows o = grp + 36k, k<3 ----
    const int grp = tid >> 4;     // 0..35
    const int ll  = tid & 15;

    int oc[3];
    const v4f* wr[3];
    #pragma unroll
    for (int k = 0; k < 3; ++k) {
        const int o = grp + 36 * k;
        oc[k] = (o < NOUT) ? o : 0;
        wr[k] = fcw4 + oc[k] * 144;
    }

    float facc[3][4] = {};

    #pragma unroll 3
    for (int jj = 0; jj < 9; ++jj) {
        const int qq = ll + 16 * jj;
        const int cc = qq / 9;               // channel of this quad

        v4f xv[4];
        #pragma unroll
        for (int vv = 0; vv < 4; ++vv) xv[vv] = xms[vv * 144 + qq];

        #pragma unroll
        for (int k = 0; k < 3; ++k) {
            const v4f  wq = wr[k][qq];
            const float a = attn_lds[oc[k] * 17 + cc];   // includes 1/15
            const float wx = a * wq.x, wy = a * wq.y, wz = a * wq.z, ww = a * wq.w;
            #pragma unroll
            for (int vv = 0; vv < 4; ++vv) {
                facc[k][vv] = fmaf(wx, xv[vv].x, facc[k][vv]);
                facc[k][vv] = fmaf(wy, xv[vv].y, facc[k][vv]);
                facc[k][vv] = fmaf(wz, xv[vv].z, facc[k][vv]);
                facc[k][vv] = fmaf(ww, xv[vv].w, facc[k][vv]);
            }
        }
    }

    // transpose-reduce within 16 lanes: lanes 0-3 end with vols 0-3
    #pragma unroll
    for (int k = 0; k < 3; ++k) {
        float rA[2];
        #pragma unroll
        for (int j = 0; j < 2; ++j) {
            const float lo = facc[k][2 * j], hi = facc[k][2 * j + 1];
            const bool  up = (ll & 1);
            const float keep = up ? hi : lo;
            const float send = up ? lo : hi;
            rA[j] = keep + __shfl_xor(send, 1, 16);
        }
        float r1;
        {
            const float lo = rA[0], hi = rA[1];
            const bool  up = (ll & 2);
            const float keep = up ? hi : lo;
            const float send = up ? lo : hi;
            r1 = keep + __shfl_xor(send, 2, 16);
        }
        r1 += __shfl_xor(r1, 4, 16);
        r1 += __shfl_xor(r1, 8, 16);         // lanes 0-3 hold vols 0-3

        const int o  = grp + 36 * k;
        const int bb = b0 + (ll & 3);
        if (ll < 4 && o < NOUT && bb < B)
            out[(size_t)bb * NOUT + o] = r1 + fcb[o];
    }
}

extern "C" void kernel_launch(void* const* d_in, const int* in_sizes, int n_in,
                              void* d_out, int out_size, void* d_ws, size_t ws_size,
                              hipStream_t stream) {
    const float* x   = (const float*)d_in[0];
    const float* dzh = (const float*)d_in[1];
    const float* dzl = (const float*)d_in[2];
    const float* fcw = (const float*)d_in[3];
    const float* fcb = (const float*)d_in[4];
    float* out = (float*)d_out;

    const int B = in_sizes[0] / (15 * 16 * 6 * 6);   // 4096
    const int blocks = (B + 3) / 4;                  // 1024

    hipLaunchKernelGGL(bodyavg_stride8, dim3(blocks), dim3(576), 0, stream,
                       reinterpret_cast<const v4f*>(x), dzh, dzl,
                       reinterpret_cast<const v4f*>(fcw), fcb, out, B);
}

// Round 14
// 33.125 us; speedup vs baseline: 1.2463x; 1.2463x over previous
//
#include <hip/hip_runtime.h>

#define NOUT 83
#define NHEART 27
#define NLUNG 28

typedef float v4f __attribute__((ext_vector_type(4)));

// forced 16B non-temporal global load (nt: bypass L1 allocation, R12's
// proven +6.5%; volatile asm: compiler cannot split/shrink the pipeline)
#define GLOADNT(dst, ptr, offs) \
    asm volatile("global_load_dwordx4 %0, %1, off offset:" offs " nt" \
                 : "=v"(dst) : "v"(ptr))

#define WAITV(lit) \
    asm volatile("s_waitcnt vmcnt(" lit ")" ::: "memory"); \
    __builtin_amdgcn_sched_barrier(0)

// Block: 512 threads = 8 waves; wave w owns volume b0+w, scans its 2160
// quads (33.75 KB) sequentially, 1 KB/step, through a ROLLING 9-deep
// pipeline: preload steps 0..8, then {vmcnt(8) -> consume oldest ->
// reissue} x24 (steps 9..32), drain 9, partial step 33. Never drains to
// empty mid-stream (R12 drained every 9 steps - the last structural gap).
// Position (64*u+l) mod 144 has period 9 -> acc[u%9], t[u%9] pair up.
// FC: 32 groups x 16 lanes; group g -> rows o = g+32k (k<3) x 8 vols.
__global__ __launch_bounds__(512) void bodyavg_roll9(
    const v4f* __restrict__ x4,      // [B*2160] quads
    const float* __restrict__ dzh,   // [27,16]
    const float* __restrict__ dzl,   // [28,16]
    const v4f* __restrict__ fcw4,    // [83,144] quads
    const float* __restrict__ fcb,   // [83]
    float* __restrict__ out,         // [B,83]
    int B)
{
    __shared__ float attn_lds[NOUT * 17];
    __shared__ v4f   xms[8 * 144];           // per-volume slice-SUM

    const int tid = threadIdx.x;
    const int blk = blockIdx.x;
    const int b0  = blk * 8;

    const int w = tid >> 6;       // wave = volume slot 0..7
    const int l = tid & 63;
    const int b = b0 + w;

    // ---- Phase 1: rolling 9-deep sequential scan, one volume per wave ----
    v4f acc[9];
    #pragma unroll
    for (int j = 0; j < 9; ++j) acc[j] = (v4f){0.f, 0.f, 0.f, 0.f};

    if (b < B) {
        const v4f* src = x4 + (size_t)b * 2160 + l;
        v4f t[9];
        // preload steps 0..8 (9 KB outstanding)
        {
            const v4f* pA = src;          // steps 0..3
            const v4f* pB = src + 256;    // steps 4..7
            GLOADNT(t[0], pA, "0");    GLOADNT(t[1], pA, "1024");
            GLOADNT(t[2], pA, "2048"); GLOADNT(t[3], pA, "3072");
            GLOADNT(t[4], pB, "0");    GLOADNT(t[5], pB, "1024");
            GLOADNT(t[6], pB, "2048"); GLOADNT(t[7], pB, "3072");
            const v4f* pC = src + 512;    // step 8
            GLOADNT(t[8], pC, "0");
        }
        // rolling steady state: steps 9..32 reissued into the slot being
        // consumed; always 9 outstanding after each reissue
        const v4f* P = src + 576;         // step 9
        #pragma unroll
        for (int u = 0; u < 24; ++u) {
            const int j = u % 9;          // static (full unroll)
            WAITV("8");                   // oldest (step u) has landed
            acc[j] += t[j];
            GLOADNT(t[j], P, "0");        // reissue step u+9
            P += 64;                      // +1024 B
        }
        // drain steps 24..32 (indices (24+d)%9 = d%9+6 pattern, static)
        WAITV("8"); acc[6] += t[6];
        WAITV("7"); acc[7] += t[7];
        WAITV("6"); acc[8] += t[8];
        WAITV("5"); acc[0] += t[0];
        WAITV("4"); acc[1] += t[1];
        WAITV("3"); acc[2] += t[2];
        WAITV("2"); acc[3] += t[3];
        WAITV("1"); acc[4] += t[4];
        WAITV("0"); acc[5] += t[5];
        // partial step 33 (48 quads), 33 mod 9 = 6
        if (l < 48) acc[6] += src[2112];
    }

    // zero own wave's region then merge (wave-private, lockstep-safe)
    {
        const v4f z = (v4f){0.f, 0.f, 0.f, 0.f};
        xms[w * 144 + l] = z;
        xms[w * 144 + 64 + l] = z;
        if (l < 16) xms[w * 144 + 128 + l] = z;
    }
    #pragma unroll
    for (int j = 0; j < 9; ++j) {
        int p = (64 * j) % 144 + l;      // < 192
        if (p >= 144) p -= 144;
        xms[w * 144 + p] += acc[j];
    }

    // ---- Phase 0: channel softmax (1/15 folded in), off critical path ----
    if (tid < NOUT) {
        const int o = tid;
        const float* row = (o < NHEART) ? (dzh + o * 16)
                                        : (dzl + ((o - NHEART) % NLUNG) * 16);
        float vals[16];
        #pragma unroll
        for (int c = 0; c < 16; ++c) vals[c] = row[c];
        float m = vals[0];
        #pragma unroll
        for (int c = 1; c < 16; ++c) m = fmaxf(m, vals[c]);
        float s = 0.f;
        #pragma unroll
        for (int c = 0; c < 16; ++c) { vals[c] = expf(vals[c] - m); s += vals[c]; }
        const float inv = (1.0f / s) * (1.0f / 15.0f);
        #pragma unroll
        for (int c = 0; c < 16; ++c) attn_lds[o * 17 + c] = vals[c] * inv;
    }

    __syncthreads();

    // ---- Phase 2: FC. 32 groups of 16 lanes; rows o = grp + 32k, k<3 ----
    const int grp = tid >> 4;     // 0..31
    const int ll  = tid & 15;

    int oc[3];
    const v4f* wr[3];
    #pragma unroll
    for (int k = 0; k < 3; ++k) {
        const int o = grp + 32 * k;
        oc[k] = (o < NOUT) ? o : 0;
        wr[k] = fcw4 + oc[k] * 144;
    }

    float facc[3][8] = {};

    #pragma unroll 3
    for (int jj = 0; jj < 9; ++jj) {
        const int q  = ll + 16 * jj;
        const int cc = q / 9;                // channel of this quad

        v4f xv[8];
        #pragma unroll
        for (int v = 0; v < 8; ++v) xv[v] = xms[v * 144 + q];

        #pragma unroll
        for (int k = 0; k < 3; ++k) {
            const v4f  wq = wr[k][q];
            const float a = attn_lds[oc[k] * 17 + cc];   // includes 1/15
            const float wx = a * wq.x, wy = a * wq.y, wz = a * wq.z, ww = a * wq.w;
            #pragma unroll
            for (int v = 0; v < 8; ++v) {
                facc[k][v] = fmaf(wx, xv[v].x, facc[k][v]);
                facc[k][v] = fmaf(wy, xv[v].y, facc[k][v]);
                facc[k][v] = fmaf(wz, xv[v].z, facc[k][v]);
                facc[k][v] = fmaf(ww, xv[v].w, facc[k][v]);
            }
        }
    }

    // transpose-reduce within 16 lanes: lanes 0-7 end with vols 0-7
    #pragma unroll
    for (int k = 0; k < 3; ++k) {
        float r4[4];
        #pragma unroll
        for (int j = 0; j < 4; ++j) {
            const float lo = facc[k][2 * j], hi = facc[k][2 * j + 1];
            const bool  up = (ll & 1);
            const float keep = up ? hi : lo;
            const float send = up ? lo : hi;
            r4[j] = keep + __shfl_xor(send, 1, 16);
        }
        float r2[2];
        #pragma unroll
        for (int j = 0; j < 2; ++j) {
            const float lo = r4[2 * j], hi = r4[2 * j + 1];
            const bool  up = (ll & 2);
            const float keep = up ? hi : lo;
            const float send = up ? lo : hi;
            r2[j] = keep + __shfl_xor(send, 2, 16);
        }
        float r1;
        {
            const float lo = r2[0], hi = r2[1];
            const bool  up = (ll & 4);
            const float keep = up ? hi : lo;
            const float send = up ? lo : hi;
            r1 = keep + __shfl_xor(send, 4, 16);
        }
        r1 += __shfl_xor(r1, 8, 16);         // lanes 0-7 hold vols 0-7

        const int o = grp + 32 * k;
        const int bb = b0 + (ll & 7);
        if (ll < 8 && o < NOUT && bb < B)
            out[(size_t)bb * NOUT + o] = r1 + fcb[o];
    }
}

extern "C" void kernel_launch(void* const* d_in, const int* in_sizes, int n_in,
                              void* d_out, int out_size, void* d_ws, size_t ws_size,
                              hipStream_t stream) {
    const float* x   = (const float*)d_in[0];
    const float* dzh = (const float*)d_in[1];
    const float* dzl = (const float*)d_in[2];
    const float* fcw = (const float*)d_in[3];
    const float* fcb = (const float*)d_in[4];
    float* out = (float*)d_out;

    const int B = in_sizes[0] / (15 * 16 * 6 * 6);   // 4096
    const int blocks = (B + 7) / 8;                  // 512

    hipLaunchKernelGGL(bodyavg_roll9, dim3(blocks), dim3(512), 0, stream,
                       reinterpret_cast<const v4f*>(x), dzh, dzl,
                       reinterpret_cast<const v4f*>(fcw), fcb, out, B);
}